// Round 1
// baseline (374.056 us; speedup 1.0000x reference)
//
#include <hip/hip_runtime.h>
#include <math.h>

// SGRUCell T=32 B=8 I=512 H=512, all f32.
// Persistent kernel: block (q=blk>>3, b=blk&7) owns rows i in [16q,16q+16) of
// batch b; 16 waves, one row per wave. Cross-block h exchange is SELF-FLAGGED:
// hn = relu(v) >= 0, so the sign bit of the stored word is a free "ready" bit.
// Producer lane0 fire-and-forget agent-stores (hn | 0x80000000); consumers poll
// the data words directly (no flag array, no waitcnt, no second round trip).
// ONE barrier per step: pre-barrier, waves 4..11 poll+fill LDS h (1 word each)
// while waves 0..3 redundantly poll their own 8 columns from global and compute
// the 4 gates (gate latency hides under the LDS fill). Post-barrier, a single
// fused m-loop does te (registers), tE/D update and both dots.
// sh_h is a 3-slot rotation: slot written at step t is read at t (cur) and t+1
// (prev); rewrite happens at t+3, and reads at t+1 complete before barrier(t+2)
// which precedes any t+3 write => race-free with one barrier/step.
// sh_gates is 2-slot (written pre-barrier(t), read post-barrier(t); next write
// of the same slot at t+2 is after barrier(t+1) => safe).
// End: per-batch done-counter rendezvous, then each block strips the sign tags
// from its own 32x16 o_outs entries (all consumers are provably done polling).

#define ATOMIC_LD(p) __hip_atomic_load((p), __ATOMIC_RELAXED, __HIP_MEMORY_SCOPE_AGENT)
#define ATOMIC_ST(p, v) __hip_atomic_store((p), (v), __ATOMIC_RELAXED, __HIP_MEMORY_SCOPE_AGENT)

__device__ __forceinline__ float wred(float v) {
#pragma unroll
  for (int o = 32; o > 0; o >>= 1) v += __shfl_xor(v, o, 64);
  return v;
}
__device__ __forceinline__ float sigm(float x) { return 1.f / (1.f + __expf(-x)); }

__global__ void prenorm_kernel(const float* __restrict__ xv, const float* __restrict__ xg,
                               const float* __restrict__ hv, const float* __restrict__ hg,
                               float* __restrict__ scx, float* __restrict__ sch,
                               unsigned* __restrict__ outs_u, unsigned* __restrict__ done) {
  int r = blockIdx.x, L = threadIdx.x;
  // outs region is poisoned (0xAA.. has sign bit set) -> must clear before persist
  if (r < 2048) outs_u[r * 64 + L] = 0u;           // 2048*64 = 131072 words
  if (r == 2048 && L < 8) done[L] = 0u;            // per-batch done counters
  const float* vrow; const float* g; float* o; int rr;
  if (r < 1536) { rr = r; vrow = xv + (size_t)r * 512; g = xg; o = scx; }
  else { rr = r - 1536; vrow = hv + (size_t)rr * 512; g = hg; o = sch; }
  float s = 0.f;
#pragma unroll
  for (int m = 0; m < 8; m++) { float v = vrow[m * 64 + L]; s = fmaf(v, v, s); }
  s = wred(s);
  if (L == 0) o[rr] = g[rr] / sqrtf(s);
}

__global__ __launch_bounds__(1024, 4) void persist_kernel(
    const float* __restrict__ x,
    const float* __restrict__ h0, const float* __restrict__ v0,
    const float* __restrict__ dU0, const float* __restrict__ te0,
    const float* __restrict__ tE0,
    const float* __restrict__ x2h_v, const float* __restrict__ x2h_b,
    const float* __restrict__ h2h_v, const float* __restrict__ h2h_b,
    const float* __restrict__ alpha,
    const float* __restrict__ h2mod_w, const float* __restrict__ h2mod_b,
    const float* __restrict__ modU_w, const float* __restrict__ modU_b,
    const float* __restrict__ scx, const float* __restrict__ sch,
    unsigned* __restrict__ done,
    float* __restrict__ o_v, float* __restrict__ o_h,
    float* __restrict__ o_dU, float* __restrict__ o_te,
    float* __restrict__ o_tE, float* __restrict__ o_outs) {
  __shared__ float sh_h[3][512];      // h rotation (6 KB)
  __shared__ float sh_mod[2048];      // h2mod_w 4x512 (8 KB)
  __shared__ float sh_mw[16][512];    // modU_w rows of this block (32 KB)
  __shared__ float sh_xpz[32][16];    // precomputed x-proj (z) + biases
  __shared__ float sh_xpdv[32][16];   // precomputed x-proj (dv) + biases
  __shared__ float sh_gates[2][4];    // double-buffered gate scalars

  const int tid = threadIdx.x;
  const int w = tid >> 6, L = tid & 63;
  const int b = blockIdx.x & 7, q = blockIdx.x >> 3;
  const int i = q * 16 + w;  // owned row

  if (tid < 512) sh_h[0][tid] = h0[b * 512 + tid];
  sh_mod[tid] = h2mod_w[tid];
  sh_mod[tid + 1024] = h2mod_w[tid + 1024];

  const int rz = i, rdv = 1024 + i, rr = 512 + i;
  const size_t row  = ((size_t)(b * 512 + i)) * 512;
  const size_t wrow = (size_t)i * 512;

  // ---- x-projection precompute FIRST (keeps register pressure low) ----
  {
    float xz[8], xdv[8];
    const float sx_z = scx[rz], sx_dv = scx[rdv];
#pragma unroll
    for (int m = 0; m < 8; m++) {
      int c = m * 64 + L;
      xz[m]  = sx_z  * x2h_v[(size_t)rz  * 512 + c];
      xdv[m] = sx_dv * x2h_v[(size_t)rdv * 512 + c];
    }
    float bz = 0.f, bdv = 0.f;
    if (L == 0) {
      bz  = x2h_b[i] + h2h_b[i];
      bdv = x2h_b[1024 + i] + h2h_b[1024 + i];
    }
#pragma unroll 4
    for (int t = 0; t < 32; t++) {
      const float* xr = x + (size_t)t * 4096 + b * 512;
      float a = 0.f, d = 0.f;
#pragma unroll
      for (int m = 0; m < 8; m++) {
        int c = m * 64 + L;
        float xv_ = xr[c];
        a = fmaf(xz[m], xv_, a);
        d = fmaf(xdv[m], xv_, d);
      }
      a = wred(a); d = wred(d);
      if (L == 0) { sh_xpz[t][w] = a + bz; sh_xpdv[t][w] = d + bdv; }
    }
  }

  // ---- persistent register tables (72 floats, same budget as prev version) ----
  float wz[8], wdv[8], mb[8], al[8], upS[8], loS[8], D[8], tE[8], te[8];
  {
    const float s_z = sch[rz], s_dv = sch[rdv], s_r = sch[rr];
#pragma unroll
    for (int m = 0; m < 8; m++) {
      int c = m * 64 + L;
      wz[m]  = s_z  * h2h_v[(size_t)rz  * 512 + c];
      wdv[m] = s_dv * h2h_v[(size_t)rdv * 512 + c];
      sh_mw[w][c] = modU_w[wrow + c];
      mb[m] = modU_b[wrow + c];
      float alv = alpha[wrow + c];
      al[m] = alv;
      float wrv = s_r * h2h_v[(size_t)rr * 512 + c];
      float t1 = alv / (alv + 1e-5f);   // alpha * (1/(alpha+eps)), prescaled
      upS[m] = fmaxf(1.f - wrv, 0.f) * t1;
      loS[m] = -fmaxf(1.f + wrv, 0.f) * t1;
      D[m]  = alv * dU0[row + c];       // scaled state: D = alpha * dU
      tE[m] = tE0[row + c];
      te[m] = te0[b * 512 + c];         // eligibility trace, in registers now
    }
  }
  float v_reg    = v0[b * 512 + i];     // identical on all lanes
  float h_cur_i  = h0[b * 512 + i];     // h_t[i]   (own row)
  float h_prev_i = 0.f;                 // h_{t-1}[i]; becomes valid at end of t=0
  float te_i     = te0[b * 512 + i];
  float gb = (w < 4) ? h2mod_b[w] : 0.f;
  __syncthreads();

  unsigned* hxu = (unsigned*)o_outs;    // h exchanged through the output buffer
  int cur = 0;                          // sh_h slot holding h_t (slot0 = h0)

  for (int t = 0; t <= 32; ++t) {
    const int prevslot = cur;
    if (t > 0) {
      cur = (cur == 2) ? 0 : cur + 1;
      const unsigned* hsrc = hxu + (size_t)(t - 1) * 4096 + b * 512;
      if (w < 4) {
        // poll own 8 columns directly from global; compute gate w pre-barrier
        unsigned u[8];
        for (;;) {
          bool ok = true;
#pragma unroll
          for (int m = 0; m < 8; m++) u[m] = ATOMIC_LD(hsrc + m * 64 + L);
#pragma unroll
          for (int m = 0; m < 8; m++) ok = ok && ((u[m] >> 31) != 0u);
          if (ok) break;
        }
        float gp = 0.f;
#pragma unroll
        for (int m = 0; m < 8; m++)
          gp = fmaf(__uint_as_float(u[m] & 0x7fffffffu),
                    sh_mod[w * 512 + m * 64 + L], gp);
        gp = wred(gp) + gb;
        if (L == 0) sh_gates[t & 1][w] = (w == 3) ? fmaxf(gp, 0.f) : sigm(gp);
      } else if (w < 12) {
        // poll one word each, fill LDS slot for this step
        const int j = tid - 256;
        unsigned u;
        do { u = ATOMIC_LD(hsrc + j); } while (!(u >> 31));
        sh_h[cur][j] = __uint_as_float(u & 0x7fffffffu);
      }
      // waves 12..15 go straight to the barrier
    }
    __syncthreads();  // the ONLY barrier per step

    float p1 = 0.f, p2 = 0.f;
    if (t > 0) {
      const float taue = sh_gates[t & 1][0], tauE = sh_gates[t & 1][1];
      const float tauU = sh_gates[t & 1][2], mU   = sh_gates[t & 1][3];
      te_i += taue * (h_prev_i - te_i);
#pragma unroll
      for (int m = 0; m < 8; m++) {
        int c = m * 64 + L;
        float hcm = sh_h[cur][c];        // h_t
        float hpm = sh_h[prevslot][c];   // h_{t-1}
        te[m] += taue * (hpm - te[m]);
        float outer = h_cur_i * te[m] - te_i * hcm;
        tE[m] += tauE * (outer - tE[m]);
        float a = fmaf(mU, sh_mw[w][c], mb[m]);
        float sshr = (a > 0.5f) ? (a - 0.5f) : ((a < -0.5f) ? (a + 0.5f) : 0.f);
        float Dn = D[m] + tauU * (sshr * (al[m] * tE[m]) - D[m]);
        D[m] = fminf(fmaxf(Dn, loS[m]), upS[m]);
        p1 = fmaf(wz[m], hcm, p1);
        p2 = fmaf(wdv[m] + D[m], hcm, p2);
      }
    } else {
#pragma unroll
      for (int m = 0; m < 8; m++) {
        float hcm = sh_h[0][m * 64 + L];
        p1 = fmaf(wz[m], hcm, p1);
        p2 = fmaf(wdv[m] + D[m], hcm, p2);
      }
    }

    if (t < 32) {
      p1 = wred(p1); p2 = wred(p2);
      float z  = sigm(p1 + sh_xpz[t][w]);
      float dv = p2 + sh_xpdv[t][w];
      v_reg += z * (dv - v_reg);
      float hn = fmaxf(v_reg, 0.f);      // >= 0: sign bit is the ready flag
      if (L == 0)
        ATOMIC_ST(hxu + (size_t)t * 4096 + b * 512 + i,
                  __float_as_uint(hn) | 0x80000000u);
      h_prev_i = h_cur_i;
      h_cur_i  = hn;
    }
  }

  // ---- final writes ----
#pragma unroll
  for (int m = 0; m < 8; m++) {
    int c = m * 64 + L;
    float alv = al[m];
    o_dU[row + c] = (alv != 0.f) ? D[m] * __builtin_amdgcn_rcpf(alv) : 0.f;
    o_tE[row + c] = tE[m];
  }
  if (L == 0) { o_v[b * 512 + i] = v_reg; o_h[b * 512 + i] = h_cur_i; }
  if (q == 0 && w == 0) {
#pragma unroll
    for (int m = 0; m < 8; m++) o_te[b * 512 + m * 64 + L] = te[m];
  }

  // ---- per-batch rendezvous, then strip the sign tags from own entries ----
  __syncthreads();
  if (tid == 0)
    __hip_atomic_fetch_add(done + b, 1u, __ATOMIC_RELAXED, __HIP_MEMORY_SCOPE_AGENT);
  if (w == 0) {
    unsigned c;
    do { c = ATOMIC_LD(done + b); } while (c < 32u);
  }
  __syncthreads();
  if (tid < 512) {  // 32 steps x 16 own rows = 512 entries
    int tt = tid >> 4, r2 = tid & 15;
    unsigned* p = hxu + (size_t)tt * 4096 + b * 512 + q * 16 + r2;
    ATOMIC_ST(p, ATOMIC_LD(p) & 0x7fffffffu);
  }
}

extern "C" void kernel_launch(void* const* d_in, const int* in_sizes, int n_in,
                              void* d_out, int out_size, void* d_ws, size_t ws_size,
                              hipStream_t stream) {
  const float* x       = (const float*)d_in[0];
  const float* h0      = (const float*)d_in[1];
  const float* v0      = (const float*)d_in[2];
  const float* dU0     = (const float*)d_in[3];
  const float* te0     = (const float*)d_in[4];
  const float* tE0     = (const float*)d_in[5];
  const float* x2h_v   = (const float*)d_in[6];
  const float* x2h_g   = (const float*)d_in[7];
  const float* x2h_b   = (const float*)d_in[8];
  const float* h2h_v   = (const float*)d_in[9];
  const float* h2h_g   = (const float*)d_in[10];
  const float* h2h_b   = (const float*)d_in[11];
  const float* alpha   = (const float*)d_in[12];
  const float* h2mod_w = (const float*)d_in[13];
  const float* h2mod_b = (const float*)d_in[14];
  const float* modU_w  = (const float*)d_in[15];
  const float* modU_b  = (const float*)d_in[16];

  float* out = (float*)d_out;
  // output layout: v(4096) h(4096) dU(2097152) te(4096) tE(2097152) outs(131072)
  float* o_v    = out;
  float* o_h    = out + 4096;
  float* o_dU   = out + 8192;
  float* o_te   = out + 2105344;
  float* o_tE   = out + 2109440;
  float* o_outs = out + 4206592;

  unsigned* done = (unsigned*)d_ws;          // 8 per-batch done counters
  float* wsf = (float*)d_ws;
  float* scx = wsf + 8192;                   // 1536
  float* sch = wsf + 9728;                   // 1536

  prenorm_kernel<<<dim3(3072), dim3(64), 0, stream>>>(
      x2h_v, x2h_g, h2h_v, h2h_g, scx, sch, (unsigned*)o_outs, done);

  persist_kernel<<<dim3(256), dim3(1024), 0, stream>>>(
      x, h0, v0, dU0, te0, tE0, x2h_v, x2h_b, h2h_v, h2h_b, alpha,
      h2mod_w, h2mod_b, modU_w, modU_b, scx, sch, done,
      o_v, o_h, o_dU, o_te, o_tE, o_outs);
}